// Round 7
// baseline (130.987 us; speedup 1.0000x reference)
//
#include <hip/hip_runtime.h>
#include <hip/hip_bf16.h>

#define DIM   384
#define HD    32
#define NH    12
#define NT    1024            // tokens per batch (32*32)
#define BATCH 8
// p = exp2(s*C2 - M2)  ==  exp(s*SCALE - 8): fixed-max softmax, scale cancels in o/l
#define C2 0.2550347244197545f    // (1/sqrt(32)) * log2(e)
#define M2 11.541560327111707f    // 8 * log2(e)

// Fragment-order layout for a k-major matrix X[row][k], K=384 (12 ksteps):
//   elem addr = ((tile16*12 + kstep)*4 + kgroup)*128 + (row&15)*8 + (k&7)
// A wave's 16x32 fragment load = 64 lanes x 16B = 1KB contiguous.

typedef short shortx8 __attribute__((ext_vector_type(8)));
typedef float floatx4 __attribute__((ext_vector_type(4)));

#define GLD_LDS(gp, lp) \
    __builtin_amdgcn_global_load_lds((__attribute__((address_space(1))) const void*)(gp), \
                                     (__attribute__((address_space(3))) void*)(lp), 16, 0, 0)

static __device__ __forceinline__ unsigned short f2bf(float f) {
    unsigned int u = __float_as_uint(f);
    u += 0x7fffu + ((u >> 16) & 1u);          // round-to-nearest-even
    return (unsigned short)(u >> 16);
}

// fragment-set load / MFMA blocks for the GEMM software-pipeline ring
template <int NA, int NB>
static __device__ __forceinline__ void ldfrag(shortx8 (&A)[NA], shortx8 (&B)[NB],
                                              const unsigned short* ab,
                                              const unsigned short* bb, int ks) {
#pragma unroll
    for (int s = 0; s < NA; s++) A[s] = *(const shortx8*)(ab + s * 6144 + ks * 512);
#pragma unroll
    for (int s = 0; s < NB; s++) B[s] = *(const shortx8*)(bb + s * 6144 + ks * 512);
}
template <int NA, int NB>
static __device__ __forceinline__ void mmblk(floatx4 (&acc)[NA][NB],
                                             const shortx8 (&A)[NA], const shortx8 (&B)[NB]) {
#pragma unroll
    for (int sm = 0; sm < NA; sm++)
#pragma unroll
        for (int sn = 0; sn < NB; sn++)
            acc[sm][sn] = __builtin_amdgcn_mfma_f32_16x16x32_bf16(A[sm], B[sn], acc[sm][sn], 0, 0, 0);
}

// ---------------------------------------------------------------------------
// Fused pre-pass. Blocks [0,3072): x (B,C,N) fp32 -> xtf bf16 A-fragment order.
// Blocks [3072,3648): W_qkv/W_proj fp32 -> bf16 B-fragment order.
__global__ __launch_bounds__(256) void k_pre(const float* __restrict__ x,
                                             const float* __restrict__ wq,
                                             const float* __restrict__ wp,
                                             unsigned short* __restrict__ xtf,
                                             unsigned short* __restrict__ wqf,
                                             unsigned short* __restrict__ wpf) {
    const int bid = blockIdx.x;
    if (bid < 3072) {
        __shared__ float t[32][33];
        const int xb_ = bid & 31, kstep = (bid >> 5) % 12, b = bid / 384;
        const int n0 = xb_ * 32;
        const int tid = threadIdx.x;
        const int tx = tid & 31, ty = tid >> 5;
        const float* xb = x + ((size_t)b * DIM + kstep * 32) * NT + n0;
#pragma unroll
        for (int i = 0; i < 4; i++)
            t[ty + 8 * i][tx] = xb[(size_t)(ty + 8 * i) * NT + tx];
        __syncthreads();
        const int mtl = tid >> 7, kq = (tid >> 5) & 3, rem = tid & 31;
        const int mrow = rem >> 1, krH = rem & 1;
        ushort4 p;
        p.x = f2bf(t[kq * 8 + krH * 4 + 0][mtl * 16 + mrow]);
        p.y = f2bf(t[kq * 8 + krH * 4 + 1][mtl * 16 + mrow]);
        p.z = f2bf(t[kq * 8 + krH * 4 + 2][mtl * 16 + mrow]);
        p.w = f2bf(t[kq * 8 + krH * 4 + 3][mtl * 16 + mrow]);
        const size_t mtile = ((size_t)b * 1024 + n0) / 16 + mtl;
        const size_t off = ((mtile * 12 + kstep) * 4 + kq) * 128 + mrow * 8 + krH * 4;
        *(ushort4*)(xtf + off) = p;
    } else {
        const int tid = (bid - 3072) * 256 + threadIdx.x;   // 0..147455
        const float* src; unsigned short* dst; int ci;
        if (tid < 110592) { ci = tid; src = wq; dst = wqf; }
        else              { ci = tid - 110592; src = wp; dst = wpf; }
        const int krH = ci & 1, orow = (ci >> 1) & 15, quad = (ci >> 5) & 3;
        const int t2 = ci >> 7, kstep = t2 % 12, ntile = t2 / 12;
        const int row = ntile * 16 + orow, col = kstep * 32 + quad * 8 + krH * 4;
        const float4 v = *(const float4*)(src + (size_t)row * DIM + col);
        ushort4 p;
        p.x = f2bf(v.x); p.y = f2bf(v.y); p.z = f2bf(v.z); p.w = f2bf(v.w);
        *(ushort4*)(dst + (size_t)ci * 4) = p;
    }
}

// ---------------------------------------------------------------------------
// QKV GEMM. 128x128 block, 4 waves x 64x64, 3-stage register prefetch ring
// (2 ksteps ahead) to cover L2 latency.
__global__ __launch_bounds__(256, 2) void k_qkv(const unsigned short* __restrict__ xtf,
                                                const unsigned short* __restrict__ wqf,
                                                unsigned short* __restrict__ qb,
                                                unsigned short* __restrict__ kb,
                                                unsigned short* __restrict__ vt) {
    const int lane = threadIdx.x & 63, w = threadIdx.x >> 6;
    const int quad = lane >> 4, l16 = lane & 15;
    const int m0 = blockIdx.x * 128 + (w & 1) * 64;
    const int n0 = blockIdx.y * 128 + (w >> 1) * 64;
    floatx4 acc[4][4] = {};
    const unsigned short* abase = xtf + ((size_t)(m0 >> 4) * 12 * 4 + quad) * 128 + l16 * 8;
    const unsigned short* bbase = wqf + ((size_t)(n0 >> 4) * 12 * 4 + quad) * 128 + l16 * 8;
    shortx8 A0[4], B0[4], A1[4], B1[4], A2[4], B2[4];
    ldfrag(A0, B0, abase, bbase, 0);
    ldfrag(A1, B1, abase, bbase, 1);
#pragma unroll
    for (int ks = 0; ks < 12; ks += 3) {
        if (ks + 2 < 12) ldfrag(A2, B2, abase, bbase, ks + 2);
        mmblk(acc, A0, B0);
        if (ks + 3 < 12) ldfrag(A0, B0, abase, bbase, ks + 3);
        mmblk(acc, A1, B1);
        if (ks + 4 < 12) ldfrag(A1, B1, abase, bbase, ks + 4);
        mmblk(acc, A2, B2);
    }
    const int bi = m0 >> 10;                     // batch constant per block
#pragma unroll
    for (int sn = 0; sn < 4; sn++) {
        const int o = n0 + sn * 16 + l16;        // 0..1151
        const int which = (o >= 2 * DIM) ? 2 : (o >= DIM ? 1 : 0);  // wave-uniform
        const int rem = o - which * DIM;
        const int h = rem >> 5, d = rem & 31;
        const int hi = bi * NH + h;
#pragma unroll
        for (int sm = 0; sm < 4; sm++) {
#pragma unroll
            for (int r = 0; r < 4; r++) {
                const int n = (m0 + sm * 16 + quad * 4 + r) & 1023;
                const unsigned short val = f2bf(acc[sm][sn][r]);
                if (which == 0)      qb[((size_t)hi * NT + n) * HD + d] = val;
                else if (which == 1) kb[((size_t)hi * NT + n) * HD + d] = val;
                else                 vt[((size_t)hi * HD + d) * NT + n] = val;
            }
        }
    }
}

// ---------------------------------------------------------------------------
// Flash attention, coarse-phase pipeline. 4 waves/block share one head.
// 32 key-tiles split into 4 phases x 8 tiles; per phase each wave DMAs its
// fragment type for all 8 tiles into LDS (global_load_lds, 16B/lane), then
// 8 tiles of barrier-free compute. Only 4 __syncthreads per block (vs 32).
// 2 Q-tiles per wave; fixed-max softmax; denominator via ones-MFMA.
__global__ __launch_bounds__(256) void k_attn(const unsigned short* __restrict__ qb,
                                              const unsigned short* __restrict__ kb,
                                              const unsigned short* __restrict__ vt,
                                              unsigned short* __restrict__ aoutf) {
    __shared__ __align__(16) unsigned short frag[2][8][4][512];   // 64 KB
    const int lane = threadIdx.x & 63, w = threadIdx.x >> 6;
    const int quad = lane >> 4, l16 = lane & 15;
    const int g = blockIdx.x & 7, j = blockIdx.x >> 3;   // 768 blocks
    const int hi = g * 12 + j % 12;                      // head instance b*NH+h
    const int q0 = ((j / 12) * 4 + w) * 32;              // 32 queries per wave
    const unsigned short* Q = qb + (size_t)hi * NT * HD;
    const unsigned short* K = kb + (size_t)hi * NT * HD;
    const unsigned short* V = vt + (size_t)hi * HD * NT;

    const shortx8 qfA = *(const shortx8*)(Q + (size_t)(q0 + l16) * HD + quad * 8);
    const shortx8 qfB = *(const shortx8*)(Q + (size_t)(q0 + 16 + l16) * HD + quad * 8);
    // permuted K-row index: A row m holds key (m>>2)*8 + (m&3)  (g0) / +4 (g1)
    const int krow = (l16 >> 2) * 8 + (l16 & 3);
    // this wave's staging source (fragment w), per-lane 16B gather:
    const unsigned short* gsrc0;
    if (w == 0)      gsrc0 = K + (size_t)krow * HD + quad * 8;
    else if (w == 1) gsrc0 = K + (size_t)(krow + 4) * HD + quad * 8;
    else if (w == 2) gsrc0 = V + (size_t)l16 * NT + quad * 8;
    else             gsrc0 = V + (size_t)(16 + l16) * NT + quad * 8;
    const int gstep = (w < 2) ? 32 * HD : 32;            // elems per 32-key tile

    const shortx8 ones = {16256, 16256, 16256, 16256, 16256, 16256, 16256, 16256}; // bf16 1.0
    floatx4 oloA = {}, ohiA = {}, dsA = {};
    floatx4 oloB = {}, ohiB = {}, dsB = {};
    const floatx4 zero = {};

#pragma unroll
    for (int t = 0; t < 8; t++)                          // stage phase 0
        GLD_LDS(gsrc0 + (size_t)t * gstep, &frag[0][t][w][0]);
    __syncthreads();

    for (int p = 0; p < 4; p++) {
        const int pb = p & 1;
        if (p < 3) {
#pragma unroll
            for (int t = 0; t < 8; t++)                  // stage phase p+1
                GLD_LDS(gsrc0 + (size_t)((p + 1) * 8 + t) * gstep, &frag[pb ^ 1][t][w][0]);
        }
#pragma unroll
        for (int t = 0; t < 8; t++) {
            const unsigned short* fb = &frag[pb][t][0][0];
            const shortx8 kf0 = *(const shortx8*)(fb + 0 * 512 + lane * 8);
            const shortx8 kf1 = *(const shortx8*)(fb + 1 * 512 + lane * 8);
            const shortx8 vlo = *(const shortx8*)(fb + 2 * 512 + lane * 8);
            const shortx8 vhi = *(const shortx8*)(fb + 3 * 512 + lane * 8);
            const floatx4 sA0 = __builtin_amdgcn_mfma_f32_16x16x32_bf16(kf0, qfA, zero, 0, 0, 0);
            const floatx4 sA1 = __builtin_amdgcn_mfma_f32_16x16x32_bf16(kf1, qfA, zero, 0, 0, 0);
            const floatx4 sB0 = __builtin_amdgcn_mfma_f32_16x16x32_bf16(kf0, qfB, zero, 0, 0, 0);
            const floatx4 sB1 = __builtin_amdgcn_mfma_f32_16x16x32_bf16(kf1, qfB, zero, 0, 0, 0);
            float eA[8], eB[8];
#pragma unroll
            for (int r = 0; r < 4; r++) {
                eA[r]     = __builtin_amdgcn_exp2f(fmaf(sA0[r], C2, -M2));
                eA[4 + r] = __builtin_amdgcn_exp2f(fmaf(sA1[r], C2, -M2));
                eB[r]     = __builtin_amdgcn_exp2f(fmaf(sB0[r], C2, -M2));
                eB[4 + r] = __builtin_amdgcn_exp2f(fmaf(sB1[r], C2, -M2));
            }
            union { shortx8 s8; __hip_bfloat162 h[4]; } pA, pB;
#pragma unroll
            for (int i = 0; i < 4; i++) {
                pA.h[i] = __float22bfloat162_rn(make_float2(eA[2 * i], eA[2 * i + 1]));
                pB.h[i] = __float22bfloat162_rn(make_float2(eB[2 * i], eB[2 * i + 1]));
            }
            oloA = __builtin_amdgcn_mfma_f32_16x16x32_bf16(pA.s8, vlo, oloA, 0, 0, 0);
            ohiA = __builtin_amdgcn_mfma_f32_16x16x32_bf16(pA.s8, vhi, ohiA, 0, 0, 0);
            dsA  = __builtin_amdgcn_mfma_f32_16x16x32_bf16(pA.s8, ones, dsA, 0, 0, 0);
            oloB = __builtin_amdgcn_mfma_f32_16x16x32_bf16(pB.s8, vlo, oloB, 0, 0, 0);
            ohiB = __builtin_amdgcn_mfma_f32_16x16x32_bf16(pB.s8, vhi, ohiB, 0, 0, 0);
            dsB  = __builtin_amdgcn_mfma_f32_16x16x32_bf16(pB.s8, ones, dsB, 0, 0, 0);
        }
        __syncthreads();   // phase p reads done everywhere; stage p+1 landed
    }
    // epilogue: write in A-fragment order (k = channel = h*32 + col)
    const int bi = hi / NH, h = hi % NH;
    const size_t mt0 = (size_t)bi * 64 + (q0 >> 4);      // mtile of tile A
    const int kqlo = l16 >> 3, kr = l16 & 7;
    unsigned short* pAp = aoutf + (mt0 * 12 + h) * 512 + kr;
    unsigned short* pBp = aoutf + ((mt0 + 1) * 12 + h) * 512 + kr;
#pragma unroll
    for (int r = 0; r < 4; r++) {
        const int mrow8 = (quad * 4 + r) * 8;
        const float invA = 1.0f / dsA[r], invB = 1.0f / dsB[r];
        pAp[kqlo * 128 + mrow8]       = f2bf(oloA[r] * invA);
        pAp[(2 + kqlo) * 128 + mrow8] = f2bf(ohiA[r] * invA);
        pBp[kqlo * 128 + mrow8]       = f2bf(oloB[r] * invB);
        pBp[(2 + kqlo) * 128 + mrow8] = f2bf(ohiB[r] * invB);
    }
}

// ---------------------------------------------------------------------------
// Proj GEMM + fp32 bias, fp32 (B, C, N) output. 64x128 block (384 blocks =
// 1.5 blocks/CU), wave tile 64x32 (A fragments shared across waves via L1),
// 3-stage prefetch ring.
__global__ __launch_bounds__(256, 2) void k_proj(const unsigned short* __restrict__ aoutf,
                                                 const unsigned short* __restrict__ wpf,
                                                 const float* __restrict__ bias,
                                                 float* __restrict__ out) {
    const int lane = threadIdx.x & 63, w = threadIdx.x >> 6;
    const int quad = lane >> 4, l16 = lane & 15;
    const int m0 = blockIdx.x * 64;
    const int n0 = blockIdx.y * 128 + w * 32;
    floatx4 acc[4][2] = {};
    const unsigned short* abase = aoutf + ((size_t)(m0 >> 4) * 12 * 4 + quad) * 128 + l16 * 8;
    const unsigned short* bbase = wpf + ((size_t)(n0 >> 4) * 12 * 4 + quad) * 128 + l16 * 8;
    shortx8 A0[4], B0[2], A1[4], B1[2], A2[4], B2[2];
    ldfrag(A0, B0, abase, bbase, 0);
    ldfrag(A1, B1, abase, bbase, 1);
#pragma unroll
    for (int ks = 0; ks < 12; ks += 3) {
        if (ks + 2 < 12) ldfrag(A2, B2, abase, bbase, ks + 2);
        mmblk(acc, A0, B0);
        if (ks + 3 < 12) ldfrag(A0, B0, abase, bbase, ks + 3);
        mmblk(acc, A1, B1);
        if (ks + 4 < 12) ldfrag(A1, B1, abase, bbase, ks + 4);
        mmblk(acc, A2, B2);
    }
    const int bi = m0 >> 10;
#pragma unroll
    for (int sn = 0; sn < 2; sn++) {
        const int o = n0 + sn * 16 + l16;
        const float bv = bias[o];
        float* orow = out + ((size_t)bi * DIM + o) * NT;
#pragma unroll
        for (int sm = 0; sm < 4; sm++) {
            const int nb = (m0 + sm * 16 + quad * 4) & 1023;
            float4 pack;
            pack.x = acc[sm][sn][0] + bv;
            pack.y = acc[sm][sn][1] + bv;
            pack.z = acc[sm][sn][2] + bv;
            pack.w = acc[sm][sn][3] + bv;
            *(float4*)(orow + nb) = pack;
        }
    }
}

// ---------------------------------------------------------------------------
extern "C" void kernel_launch(void* const* d_in, const int* in_sizes, int n_in,
                              void* d_out, int out_size, void* d_ws, size_t ws_size,
                              hipStream_t stream) {
    const float* x     = (const float*)d_in[0];
    const float* wqkv  = (const float*)d_in[1];
    const float* wproj = (const float*)d_in[2];
    const float* bias  = (const float*)d_in[3];
    float* out = (float*)d_out;

    // ws layout (bf16 elems): xtf | q | k | vT | wqf | wpf ; aoutf reuses xtf.
    unsigned short* xtf  = (unsigned short*)d_ws;
    unsigned short* qb   = xtf + 3145728;
    unsigned short* kb   = qb + 3145728;
    unsigned short* vt   = kb + 3145728;
    unsigned short* wqf  = vt + 3145728;
    unsigned short* wpf  = wqf + 442368;
    unsigned short* aoutf = xtf;                  // xtf dead after k_qkv

    k_pre<<<3648, 256, 0, stream>>>(x, wqkv, wproj, xtf, wqf, wpf);
    k_qkv<<<dim3(64, 9), 256, 0, stream>>>(xtf, wqf, qb, kb, vt);
    k_attn<<<768, 256, 0, stream>>>(qb, kb, vt, aoutf);
    k_proj<<<dim3(128, 3), 256, 0, stream>>>(aoutf, wpf, bias, out);
}

// Round 8
// 122.603 us; speedup vs baseline: 1.0684x; 1.0684x over previous
//
#include <hip/hip_runtime.h>
#include <hip/hip_bf16.h>

#define DIM   384
#define HD    32
#define NH    12
#define NT    1024            // tokens per batch (32*32)
#define BATCH 8
// p = exp2(s*C2 - M2)  ==  exp(s*SCALE - 8): fixed-max softmax, scale cancels in o/l
#define C2 0.2550347244197545f    // (1/sqrt(32)) * log2(e)
#define M2 11.541560327111707f    // 8 * log2(e)

// Fragment-order layout for a k-major matrix X[row][k], K=384 (12 ksteps):
//   elem addr = ((tile16*12 + kstep)*4 + kgroup)*128 + (row&15)*8 + (k&7)
// A wave's 16x32 fragment load = 64 lanes x 16B = 1KB contiguous.
// KV fragment buffer: kvf[head][tile32][frag][512], frag0/1 = K rows in the
// S^T permutation, frag2/3 = V rows d=0..15 / 16..31 — so attention staging
// DMAs are 1KB contiguous (frag = what one wave feeds one MFMA operand).

typedef short shortx8 __attribute__((ext_vector_type(8)));
typedef float floatx4 __attribute__((ext_vector_type(4)));

#define GLD_LDS(gp, lp) \
    __builtin_amdgcn_global_load_lds((__attribute__((address_space(1))) const void*)(gp), \
                                     (__attribute__((address_space(3))) void*)(lp), 16, 0, 0)

static __device__ __forceinline__ unsigned short f2bf(float f) {
    unsigned int u = __float_as_uint(f);
    u += 0x7fffu + ((u >> 16) & 1u);          // round-to-nearest-even
    return (unsigned short)(u >> 16);
}

// fragment-set load / MFMA blocks for the GEMM software-pipeline ring
template <int NA, int NB>
static __device__ __forceinline__ void ldfrag(shortx8 (&A)[NA], shortx8 (&B)[NB],
                                              const unsigned short* ab,
                                              const unsigned short* bb, int ks) {
#pragma unroll
    for (int s = 0; s < NA; s++) A[s] = *(const shortx8*)(ab + s * 6144 + ks * 512);
#pragma unroll
    for (int s = 0; s < NB; s++) B[s] = *(const shortx8*)(bb + s * 6144 + ks * 512);
}
template <int NA, int NB>
static __device__ __forceinline__ void mmblk(floatx4 (&acc)[NA][NB],
                                             const shortx8 (&A)[NA], const shortx8 (&B)[NB]) {
#pragma unroll
    for (int sm = 0; sm < NA; sm++)
#pragma unroll
        for (int sn = 0; sn < NB; sn++)
            acc[sm][sn] = __builtin_amdgcn_mfma_f32_16x16x32_bf16(A[sm], B[sn], acc[sm][sn], 0, 0, 0);
}

// ---------------------------------------------------------------------------
// Fused pre-pass. Blocks [0,3072): x (B,C,N) fp32 -> xtf bf16 A-fragment order.
// Blocks [3072,3648): W_qkv/W_proj fp32 -> bf16 B-fragment order.
__global__ __launch_bounds__(256) void k_pre(const float* __restrict__ x,
                                             const float* __restrict__ wq,
                                             const float* __restrict__ wp,
                                             unsigned short* __restrict__ xtf,
                                             unsigned short* __restrict__ wqf,
                                             unsigned short* __restrict__ wpf) {
    const int bid = blockIdx.x;
    if (bid < 3072) {
        __shared__ float t[32][33];
        const int xb_ = bid & 31, kstep = (bid >> 5) % 12, b = bid / 384;
        const int n0 = xb_ * 32;
        const int tid = threadIdx.x;
        const int tx = tid & 31, ty = tid >> 5;
        const float* xb = x + ((size_t)b * DIM + kstep * 32) * NT + n0;
#pragma unroll
        for (int i = 0; i < 4; i++)
            t[ty + 8 * i][tx] = xb[(size_t)(ty + 8 * i) * NT + tx];
        __syncthreads();
        const int mtl = tid >> 7, kq = (tid >> 5) & 3, rem = tid & 31;
        const int mrow = rem >> 1, krH = rem & 1;
        ushort4 p;
        p.x = f2bf(t[kq * 8 + krH * 4 + 0][mtl * 16 + mrow]);
        p.y = f2bf(t[kq * 8 + krH * 4 + 1][mtl * 16 + mrow]);
        p.z = f2bf(t[kq * 8 + krH * 4 + 2][mtl * 16 + mrow]);
        p.w = f2bf(t[kq * 8 + krH * 4 + 3][mtl * 16 + mrow]);
        const size_t mtile = ((size_t)b * 1024 + n0) / 16 + mtl;
        const size_t off = ((mtile * 12 + kstep) * 4 + kq) * 128 + mrow * 8 + krH * 4;
        *(ushort4*)(xtf + off) = p;
    } else {
        const int tid = (bid - 3072) * 256 + threadIdx.x;   // 0..147455
        const float* src; unsigned short* dst; int ci;
        if (tid < 110592) { ci = tid; src = wq; dst = wqf; }
        else              { ci = tid - 110592; src = wp; dst = wpf; }
        const int krH = ci & 1, orow = (ci >> 1) & 15, quad = (ci >> 5) & 3;
        const int t2 = ci >> 7, kstep = t2 % 12, ntile = t2 / 12;
        const int row = ntile * 16 + orow, col = kstep * 32 + quad * 8 + krH * 4;
        const float4 v = *(const float4*)(src + (size_t)row * DIM + col);
        ushort4 p;
        p.x = f2bf(v.x); p.y = f2bf(v.y); p.z = f2bf(v.z); p.w = f2bf(v.w);
        *(ushort4*)(dst + (size_t)ci * 4) = p;
    }
}

// ---------------------------------------------------------------------------
// QKV GEMM. 128x96 block (grid 64x12 = 768 = exactly 3 blocks/CU, no tail),
// 4 waves x 64x48 (acc[4][3]), 2-stage register prefetch ring.
// Epilogue: q row-major (b,h,n,d); K/V into kvf fragment order (see header).
__global__ __launch_bounds__(256, 3) void k_qkv(const unsigned short* __restrict__ xtf,
                                                const unsigned short* __restrict__ wqf,
                                                unsigned short* __restrict__ qb,
                                                unsigned short* __restrict__ kvf) {
    const int lane = threadIdx.x & 63, w = threadIdx.x >> 6;
    const int quad = lane >> 4, l16 = lane & 15;
    const int m0 = blockIdx.x * 128 + (w & 1) * 64;
    const int n0 = blockIdx.y * 96 + (w >> 1) * 48;
    floatx4 acc[4][3] = {};
    const unsigned short* abase = xtf + ((size_t)(m0 >> 4) * 48 + quad) * 128 + l16 * 8;
    const unsigned short* bbase = wqf + ((size_t)(n0 >> 4) * 48 + quad) * 128 + l16 * 8;
    shortx8 A0[4], B0[3], A1[4], B1[3];
    ldfrag(A0, B0, abase, bbase, 0);
#pragma unroll
    for (int ks = 0; ks < 12; ks += 2) {
        if (ks + 1 < 12) ldfrag(A1, B1, abase, bbase, ks + 1);
        mmblk(acc, A0, B0);
        if (ks + 2 < 12) ldfrag(A0, B0, abase, bbase, ks + 2);
        mmblk(acc, A1, B1);
    }
    const int bi = m0 >> 10;                     // batch constant per block
#pragma unroll
    for (int sn = 0; sn < 3; sn++) {
        const int o = n0 + sn * 16 + l16;        // 0..1151
        const int which = (o >= 2 * DIM) ? 2 : (o >= DIM ? 1 : 0);  // wave-uniform
        const int rem = o - which * DIM;
        const int h = rem >> 5, d = rem & 31;
        const size_t hi = (size_t)bi * NH + h;
#pragma unroll
        for (int sm = 0; sm < 4; sm++) {
#pragma unroll
            for (int r = 0; r < 4; r++) {
                const int n = (m0 + sm * 16 + quad * 4 + r) & 1023;
                const unsigned short val = f2bf(acc[sm][sn][r]);
                if (which == 0) {
                    qb[(hi * NT + n) * HD + d] = val;
                } else if (which == 1) {
                    // K: frag 0/1, row = S^T permutation of key-in-tile
                    const int key = n & 31;
                    const int kf_ = ((key & 7) < 4) ? 0 : 1;
                    const int kk = key - 4 * kf_;
                    const int l16p = ((kk >> 3) << 2) | (kk & 3);
                    const int pos = (l16p + 16 * (d >> 3)) * 8 + (d & 7);
                    kvf[((hi * 32 + (n >> 5)) * 4 + kf_) * 512 + pos] = val;
                } else {
                    // V: frag 2/3, lane = (d&15) + 16*key-octet, elem = key&7
                    const int f = 2 + (d >> 4);
                    const int ln = (d & 15) + 16 * ((n & 31) >> 3);
                    const int pos = ln * 8 + (n & 7);
                    kvf[((hi * 32 + (n >> 5)) * 4 + f) * 512 + pos] = val;
                }
            }
        }
    }
}

// ---------------------------------------------------------------------------
// Flash attention. 4 waves/block, one head/block-group; per 32-key tile the
// 4 fragments are pre-packed contiguously in kvf — each wave DMAs its frag
// (1KB contiguous) for 4 tiles/phase, double-buffered (32 KB LDS, 8 barriers,
// 3 blocks/CU co-resident, grid 768 = 3*256: zero tail).
// 2 Q-tiles per wave; fixed-max softmax; denominator via ones-MFMA.
__global__ __launch_bounds__(256, 3) void k_attn(const unsigned short* __restrict__ qb,
                                                 const unsigned short* __restrict__ kvf,
                                                 unsigned short* __restrict__ aoutf) {
    __shared__ __align__(16) unsigned short frag[2][4][4][512];   // 32 KB
    const int lane = threadIdx.x & 63, w = threadIdx.x >> 6;
    const int quad = lane >> 4, l16 = lane & 15;
    const int g = blockIdx.x & 7, j = blockIdx.x >> 3;   // 768 blocks
    const int hi = g * 12 + j % 12;                      // head instance b*NH+h
    const int q0 = ((j / 12) * 4 + w) * 32;              // 32 queries per wave
    const unsigned short* Q = qb + (size_t)hi * NT * HD;

    const shortx8 qfA = *(const shortx8*)(Q + (size_t)(q0 + l16) * HD + quad * 8);
    const shortx8 qfB = *(const shortx8*)(Q + (size_t)(q0 + 16 + l16) * HD + quad * 8);
    // this wave's staging source: fragment w of each tile, contiguous 1KB
    const unsigned short* gsrc = kvf + ((size_t)hi * 32 * 4 + w) * 512 + lane * 8;
    const int gstep = 4 * 512;                           // elems per 32-key tile

    const shortx8 ones = {16256, 16256, 16256, 16256, 16256, 16256, 16256, 16256}; // bf16 1.0
    floatx4 oloA = {}, ohiA = {}, dsA = {};
    floatx4 oloB = {}, ohiB = {}, dsB = {};
    const floatx4 zero = {};

#pragma unroll
    for (int t = 0; t < 4; t++)                          // stage phase 0
        GLD_LDS(gsrc + (size_t)t * gstep, &frag[0][t][w][0]);
    __syncthreads();

    for (int p = 0; p < 8; p++) {
        const int pb = p & 1;
        if (p < 7) {
#pragma unroll
            for (int t = 0; t < 4; t++)                  // stage phase p+1
                GLD_LDS(gsrc + (size_t)((p + 1) * 4 + t) * gstep, &frag[pb ^ 1][t][w][0]);
        }
#pragma unroll
        for (int t = 0; t < 4; t++) {
            const unsigned short* fb = &frag[pb][t][0][0];
            const shortx8 kf0 = *(const shortx8*)(fb + 0 * 512 + lane * 8);
            const shortx8 kf1 = *(const shortx8*)(fb + 1 * 512 + lane * 8);
            const shortx8 vlo = *(const shortx8*)(fb + 2 * 512 + lane * 8);
            const shortx8 vhi = *(const shortx8*)(fb + 3 * 512 + lane * 8);
            const floatx4 sA0 = __builtin_amdgcn_mfma_f32_16x16x32_bf16(kf0, qfA, zero, 0, 0, 0);
            const floatx4 sA1 = __builtin_amdgcn_mfma_f32_16x16x32_bf16(kf1, qfA, zero, 0, 0, 0);
            const floatx4 sB0 = __builtin_amdgcn_mfma_f32_16x16x32_bf16(kf0, qfB, zero, 0, 0, 0);
            const floatx4 sB1 = __builtin_amdgcn_mfma_f32_16x16x32_bf16(kf1, qfB, zero, 0, 0, 0);
            float eA[8], eB[8];
#pragma unroll
            for (int r = 0; r < 4; r++) {
                eA[r]     = __builtin_amdgcn_exp2f(fmaf(sA0[r], C2, -M2));
                eA[4 + r] = __builtin_amdgcn_exp2f(fmaf(sA1[r], C2, -M2));
                eB[r]     = __builtin_amdgcn_exp2f(fmaf(sB0[r], C2, -M2));
                eB[4 + r] = __builtin_amdgcn_exp2f(fmaf(sB1[r], C2, -M2));
            }
            union { shortx8 s8; __hip_bfloat162 h[4]; } pA, pB;
#pragma unroll
            for (int i = 0; i < 4; i++) {
                pA.h[i] = __float22bfloat162_rn(make_float2(eA[2 * i], eA[2 * i + 1]));
                pB.h[i] = __float22bfloat162_rn(make_float2(eB[2 * i], eB[2 * i + 1]));
            }
            oloA = __builtin_amdgcn_mfma_f32_16x16x32_bf16(pA.s8, vlo, oloA, 0, 0, 0);
            ohiA = __builtin_amdgcn_mfma_f32_16x16x32_bf16(pA.s8, vhi, ohiA, 0, 0, 0);
            dsA  = __builtin_amdgcn_mfma_f32_16x16x32_bf16(pA.s8, ones, dsA, 0, 0, 0);
            oloB = __builtin_amdgcn_mfma_f32_16x16x32_bf16(pB.s8, vlo, oloB, 0, 0, 0);
            ohiB = __builtin_amdgcn_mfma_f32_16x16x32_bf16(pB.s8, vhi, ohiB, 0, 0, 0);
            dsB  = __builtin_amdgcn_mfma_f32_16x16x32_bf16(pB.s8, ones, dsB, 0, 0, 0);
        }
        __syncthreads();   // phase p reads done everywhere; stage p+1 landed
    }
    // epilogue: write in A-fragment order (k = channel = h*32 + col)
    const int bi = hi / NH, h = hi % NH;
    const size_t mt0 = (size_t)bi * 64 + (q0 >> 4);      // mtile of tile A
    const int kqlo = l16 >> 3, kr = l16 & 7;
    unsigned short* pAp = aoutf + (mt0 * 12 + h) * 512 + kr;
    unsigned short* pBp = aoutf + ((mt0 + 1) * 12 + h) * 512 + kr;
#pragma unroll
    for (int r = 0; r < 4; r++) {
        const int mrow8 = (quad * 4 + r) * 8;
        const float invA = 1.0f / dsA[r], invB = 1.0f / dsB[r];
        pAp[kqlo * 128 + mrow8]       = f2bf(oloA[r] * invA);
        pAp[(2 + kqlo) * 128 + mrow8] = f2bf(ohiA[r] * invA);
        pBp[kqlo * 128 + mrow8]       = f2bf(oloB[r] * invB);
        pBp[(2 + kqlo) * 128 + mrow8] = f2bf(ohiB[r] * invB);
    }
}

// ---------------------------------------------------------------------------
// Proj GEMM + fp32 bias, fp32 (B, C, N) output. 64x64 block, 4 waves x 32x32,
// grid (128,6) = 768 = 3 blocks/CU exactly, 2-stage prefetch ring.
__global__ __launch_bounds__(256, 3) void k_proj(const unsigned short* __restrict__ aoutf,
                                                 const unsigned short* __restrict__ wpf,
                                                 const float* __restrict__ bias,
                                                 float* __restrict__ out) {
    const int lane = threadIdx.x & 63, w = threadIdx.x >> 6;
    const int quad = lane >> 4, l16 = lane & 15;
    const int m0 = blockIdx.x * 64 + (w & 1) * 32;
    const int n0 = blockIdx.y * 64 + (w >> 1) * 32;
    floatx4 acc[2][2] = {};
    const unsigned short* abase = aoutf + ((size_t)(m0 >> 4) * 48 + quad) * 128 + l16 * 8;
    const unsigned short* bbase = wpf + ((size_t)(n0 >> 4) * 48 + quad) * 128 + l16 * 8;
    shortx8 A0[2], B0[2], A1[2], B1[2];
    ldfrag(A0, B0, abase, bbase, 0);
#pragma unroll
    for (int ks = 0; ks < 12; ks += 2) {
        if (ks + 1 < 12) ldfrag(A1, B1, abase, bbase, ks + 1);
        mmblk(acc, A0, B0);
        if (ks + 2 < 12) ldfrag(A0, B0, abase, bbase, ks + 2);
        mmblk(acc, A1, B1);
    }
    const int bi = m0 >> 10;
#pragma unroll
    for (int sn = 0; sn < 2; sn++) {
        const int o = n0 + sn * 16 + l16;
        const float bv = bias[o];
        float* orow = out + ((size_t)bi * DIM + o) * NT;
#pragma unroll
        for (int sm = 0; sm < 2; sm++) {
            const int nb = (m0 + sm * 16 + quad * 4) & 1023;
            float4 pack;
            pack.x = acc[sm][sn][0] + bv;
            pack.y = acc[sm][sn][1] + bv;
            pack.z = acc[sm][sn][2] + bv;
            pack.w = acc[sm][sn][3] + bv;
            *(float4*)(orow + nb) = pack;
        }
    }
}

// ---------------------------------------------------------------------------
extern "C" void kernel_launch(void* const* d_in, const int* in_sizes, int n_in,
                              void* d_out, int out_size, void* d_ws, size_t ws_size,
                              hipStream_t stream) {
    const float* x     = (const float*)d_in[0];
    const float* wqkv  = (const float*)d_in[1];
    const float* wproj = (const float*)d_in[2];
    const float* bias  = (const float*)d_in[3];
    float* out = (float*)d_out;

    // ws layout (bf16 elems): xtf | qb | kvf | wqf | wpf ; aoutf reuses xtf.
    unsigned short* xtf  = (unsigned short*)d_ws;
    unsigned short* qb   = xtf + 3145728;
    unsigned short* kvf  = qb + 3145728;
    unsigned short* wqf  = kvf + 6291456;    // 96*32*4*512
    unsigned short* wpf  = wqf + 442368;
    unsigned short* aoutf = xtf;             // xtf dead after k_qkv

    k_pre<<<3648, 256, 0, stream>>>(x, wqkv, wproj, xtf, wqf, wpf);
    k_qkv<<<dim3(64, 12), 256, 0, stream>>>(xtf, wqf, qb, kvf);
    k_attn<<<768, 256, 0, stream>>>(qb, kvf, aoutf);
    k_proj<<<dim3(128, 6), 256, 0, stream>>>(aoutf, wpf, bias, out);
}

// Round 10
// 122.194 us; speedup vs baseline: 1.0720x; 1.0033x over previous
//
#include <hip/hip_runtime.h>
#include <hip/hip_bf16.h>

#define DIM   384
#define HD    32
#define NH    12
#define NT    1024            // tokens per batch (32*32)
#define BATCH 8
// p = exp2(s*C2 - M2)  ==  exp(s*SCALE - 8): fixed-max softmax, scale cancels in o/l
#define C2 0.2550347244197545f    // (1/sqrt(32)) * log2(e)
#define M2 11.541560327111707f    // 8 * log2(e)

// Fragment-order layout for a k-major matrix X[row][k], K=384 (12 ksteps):
//   elem addr = ((tile16*12 + kstep)*4 + kgroup)*128 + (row&15)*8 + (k&7)
// KV fragment buffer: kvf[head][tile32][frag][512], frag0/1 = K rows in the
// S^T permutation, frag2/3 = V rows d=0..15 / 16..31 — attention staging
// DMAs are 1KB contiguous.

typedef short shortx8 __attribute__((ext_vector_type(8)));
typedef float floatx4 __attribute__((ext_vector_type(4)));

#define GLD_LDS(gp, lp) \
    __builtin_amdgcn_global_load_lds((__attribute__((address_space(1))) const void*)(gp), \
                                     (__attribute__((address_space(3))) void*)(lp), 16, 0, 0)

static __device__ __forceinline__ unsigned short f2bf(float f) {
    unsigned int u = __float_as_uint(f);
    u += 0x7fffu + ((u >> 16) & 1u);          // round-to-nearest-even
    return (unsigned short)(u >> 16);
}

// fragment-set load / MFMA blocks for the GEMM software-pipeline ring
template <int NA, int NB>
static __device__ __forceinline__ void ldfrag(shortx8 (&A)[NA], shortx8 (&B)[NB],
                                              const unsigned short* ab,
                                              const unsigned short* bb, int ks) {
#pragma unroll
    for (int s = 0; s < NA; s++) A[s] = *(const shortx8*)(ab + s * 6144 + ks * 512);
#pragma unroll
    for (int s = 0; s < NB; s++) B[s] = *(const shortx8*)(bb + s * 6144 + ks * 512);
}
template <int NA, int NB>
static __device__ __forceinline__ void mmblk(floatx4 (&acc)[NA][NB],
                                             const shortx8 (&A)[NA], const shortx8 (&B)[NB]) {
#pragma unroll
    for (int sm = 0; sm < NA; sm++)
#pragma unroll
        for (int sn = 0; sn < NB; sn++)
            acc[sm][sn] = __builtin_amdgcn_mfma_f32_16x16x32_bf16(A[sm], B[sn], acc[sm][sn], 0, 0, 0);
}

// ---------------------------------------------------------------------------
// Fused pre-pass. Blocks [0,3072): x (B,C,N) fp32 -> xtf bf16 A-fragment order
// (float4 tile loads). Blocks [3072,3648): W_qkv/W_proj -> bf16 B-fragment order.
__global__ __launch_bounds__(256) void k_pre(const float* __restrict__ x,
                                             const float* __restrict__ wq,
                                             const float* __restrict__ wp,
                                             unsigned short* __restrict__ xtf,
                                             unsigned short* __restrict__ wqf,
                                             unsigned short* __restrict__ wpf) {
    const int bid = blockIdx.x;
    if (bid < 3072) {
        __shared__ float t[32][33];
        const int xb_ = bid & 31, kstep = (bid >> 5) % 12, b = bid / 384;
        const int n0 = xb_ * 32;
        const int tid = threadIdx.x;
        const int row = tid >> 3, col4 = (tid & 7) * 4;       // one float4/thread
        const float* xb = x + ((size_t)b * DIM + kstep * 32) * NT + n0;
        const float4 v4 = *(const float4*)(xb + (size_t)row * NT + col4);
        t[row][col4 + 0] = v4.x;
        t[row][col4 + 1] = v4.y;
        t[row][col4 + 2] = v4.z;
        t[row][col4 + 3] = v4.w;
        __syncthreads();
        const int mtl = tid >> 7, kq = (tid >> 5) & 3, rem = tid & 31;
        const int mrow = rem >> 1, krH = rem & 1;
        ushort4 p;
        p.x = f2bf(t[kq * 8 + krH * 4 + 0][mtl * 16 + mrow]);
        p.y = f2bf(t[kq * 8 + krH * 4 + 1][mtl * 16 + mrow]);
        p.z = f2bf(t[kq * 8 + krH * 4 + 2][mtl * 16 + mrow]);
        p.w = f2bf(t[kq * 8 + krH * 4 + 3][mtl * 16 + mrow]);
        const size_t mtile = ((size_t)b * 1024 + n0) / 16 + mtl;
        const size_t off = ((mtile * 12 + kstep) * 4 + kq) * 128 + mrow * 8 + krH * 4;
        *(ushort4*)(xtf + off) = p;
    } else {
        const int tid = (bid - 3072) * 256 + threadIdx.x;   // 0..147455
        const float* src; unsigned short* dst; int ci;
        if (tid < 110592) { ci = tid; src = wq; dst = wqf; }
        else              { ci = tid - 110592; src = wp; dst = wpf; }
        const int krH = ci & 1, orow = (ci >> 1) & 15, quad = (ci >> 5) & 3;
        const int t2 = ci >> 7, kstep = t2 % 12, ntile = t2 / 12;
        const int row = ntile * 16 + orow, col = kstep * 32 + quad * 8 + krH * 4;
        const float4 v = *(const float4*)(src + (size_t)row * DIM + col);
        ushort4 p;
        p.x = f2bf(v.x); p.y = f2bf(v.y); p.z = f2bf(v.z); p.w = f2bf(v.w);
        *(ushort4*)(dst + (size_t)ci * 4) = p;
    }
}

// ---------------------------------------------------------------------------
// QKV GEMM. 128x96 block (grid 64x12 = 768 = exactly 3 blocks/CU, no tail),
// 4 waves x 64x48 (acc[4][3]), 2-stage register prefetch ring.
// Epilogue: q row-major (b,h,n,d); K/V into kvf fragment order (see header);
// V stores vectorized ushort4 (4 consecutive keys are contiguous in kvf).
__global__ __launch_bounds__(256, 3) void k_qkv(const unsigned short* __restrict__ xtf,
                                                const unsigned short* __restrict__ wqf,
                                                unsigned short* __restrict__ qb,
                                                unsigned short* __restrict__ kvf) {
    const int lane = threadIdx.x & 63, w = threadIdx.x >> 6;
    const int quad = lane >> 4, l16 = lane & 15;
    const int m0 = blockIdx.x * 128 + (w & 1) * 64;
    const int n0 = blockIdx.y * 96 + (w >> 1) * 48;
    floatx4 acc[4][3] = {};
    const unsigned short* abase = xtf + ((size_t)(m0 >> 4) * 48 + quad) * 128 + l16 * 8;
    const unsigned short* bbase = wqf + ((size_t)(n0 >> 4) * 48 + quad) * 128 + l16 * 8;
    shortx8 A0[4], B0[3], A1[4], B1[3];
    ldfrag(A0, B0, abase, bbase, 0);
#pragma unroll
    for (int ks = 0; ks < 12; ks += 2) {
        if (ks + 1 < 12) ldfrag(A1, B1, abase, bbase, ks + 1);
        mmblk(acc, A0, B0);
        if (ks + 2 < 12) ldfrag(A0, B0, abase, bbase, ks + 2);
        mmblk(acc, A1, B1);
    }
    const int bi = m0 >> 10;                     // batch constant per block
#pragma unroll
    for (int sn = 0; sn < 3; sn++) {
        const int o = n0 + sn * 16 + l16;        // 0..1151
        const int which = (o >= 2 * DIM) ? 2 : (o >= DIM ? 1 : 0);  // wave-uniform
        const int rem = o - which * DIM;
        const int h = rem >> 5, d = rem & 31;
        const size_t hi = (size_t)bi * NH + h;
#pragma unroll
        for (int sm = 0; sm < 4; sm++) {
            if (which == 2) {
                // V: frag 2/3; 4 consecutive keys (regs) are contiguous elems
                const int nb = m0 + sm * 16 + quad * 4;      // n for r=0
                const int n_ = nb & 1023;
                const int f = 2 + (d >> 4);
                const int ln = (d & 15) + 16 * ((n_ & 31) >> 3);
                ushort4 p;
                p.x = f2bf(acc[sm][sn][0]);
                p.y = f2bf(acc[sm][sn][1]);
                p.z = f2bf(acc[sm][sn][2]);
                p.w = f2bf(acc[sm][sn][3]);
                *(ushort4*)(kvf + ((hi * 32 + (n_ >> 5)) * 4 + f) * 512 + ln * 8 + (n_ & 7)) = p;
            } else {
#pragma unroll
                for (int r = 0; r < 4; r++) {
                    const int n = (m0 + sm * 16 + quad * 4 + r) & 1023;
                    const unsigned short val = f2bf(acc[sm][sn][r]);
                    if (which == 0) {
                        qb[(hi * NT + n) * HD + d] = val;
                    } else {
                        const int key = n & 31;
                        const int kf_ = ((key & 7) < 4) ? 0 : 1;
                        const int kk = key - 4 * kf_;
                        const int l16p = ((kk >> 3) << 2) | (kk & 3);
                        const int pos = (l16p + 16 * (d >> 3)) * 8 + (d & 7);
                        kvf[((hi * 32 + (n >> 5)) * 4 + kf_) * 512 + pos] = val;
                    }
                }
            }
        }
    }
}

// ---------------------------------------------------------------------------
// Flash attention. 4 waves/block, one head/block-group; per 32-key tile the
// 4 fragments are pre-packed contiguously in kvf — each wave DMAs its frag
// (1KB contiguous) for 4 tiles/phase, double-buffered (32 KB LDS, 8 barriers,
// 3 blocks/CU co-resident, grid 768 = 3*256: zero tail).
// 2 Q-tiles per wave; fixed-max softmax; denominator via ones-MFMA.
__global__ __launch_bounds__(256, 3) void k_attn(const unsigned short* __restrict__ qb,
                                                 const unsigned short* __restrict__ kvf,
                                                 unsigned short* __restrict__ aoutf) {
    __shared__ __align__(16) unsigned short frag[2][4][4][512];   // 32 KB
    const int lane = threadIdx.x & 63, w = threadIdx.x >> 6;
    const int quad = lane >> 4, l16 = lane & 15;
    const int g = blockIdx.x & 7, j = blockIdx.x >> 3;   // 768 blocks
    const int hi = g * 12 + j % 12;                      // head instance b*NH+h
    const int q0 = ((j / 12) * 4 + w) * 32;              // 32 queries per wave
    const unsigned short* Q = qb + (size_t)hi * NT * HD;

    const shortx8 qfA = *(const shortx8*)(Q + (size_t)(q0 + l16) * HD + quad * 8);
    const shortx8 qfB = *(const shortx8*)(Q + (size_t)(q0 + 16 + l16) * HD + quad * 8);
    // this wave's staging source: fragment w of each tile, contiguous 1KB
    const unsigned short* gsrc = kvf + ((size_t)hi * 32 * 4 + w) * 512 + lane * 8;
    const int gstep = 4 * 512;                           // elems per 32-key tile

    const shortx8 ones = {16256, 16256, 16256, 16256, 16256, 16256, 16256, 16256}; // bf16 1.0
    floatx4 oloA = {}, ohiA = {}, dsA = {};
    floatx4 oloB = {}, ohiB = {}, dsB = {};
    const floatx4 zero = {};

#pragma unroll
    for (int t = 0; t < 4; t++)                          // stage phase 0
        GLD_LDS(gsrc + (size_t)t * gstep, &frag[0][t][w][0]);
    __syncthreads();

    for (int p = 0; p < 8; p++) {
        const int pb = p & 1;
        if (p < 7) {
#pragma unroll
            for (int t = 0; t < 4; t++)                  // stage phase p+1
                GLD_LDS(gsrc + (size_t)((p + 1) * 4 + t) * gstep, &frag[pb ^ 1][t][w][0]);
        }
#pragma unroll
        for (int t = 0; t < 4; t++) {
            const unsigned short* fb = &frag[pb][t][0][0];
            const shortx8 kf0 = *(const shortx8*)(fb + 0 * 512 + lane * 8);
            const shortx8 kf1 = *(const shortx8*)(fb + 1 * 512 + lane * 8);
            const shortx8 vlo = *(const shortx8*)(fb + 2 * 512 + lane * 8);
            const shortx8 vhi = *(const shortx8*)(fb + 3 * 512 + lane * 8);
            const floatx4 sA0 = __builtin_amdgcn_mfma_f32_16x16x32_bf16(kf0, qfA, zero, 0, 0, 0);
            const floatx4 sA1 = __builtin_amdgcn_mfma_f32_16x16x32_bf16(kf1, qfA, zero, 0, 0, 0);
            const floatx4 sB0 = __builtin_amdgcn_mfma_f32_16x16x32_bf16(kf0, qfB, zero, 0, 0, 0);
            const floatx4 sB1 = __builtin_amdgcn_mfma_f32_16x16x32_bf16(kf1, qfB, zero, 0, 0, 0);
            float eA[8], eB[8];
#pragma unroll
            for (int r = 0; r < 4; r++) {
                eA[r]     = __builtin_amdgcn_exp2f(fmaf(sA0[r], C2, -M2));
                eA[4 + r] = __builtin_amdgcn_exp2f(fmaf(sA1[r], C2, -M2));
                eB[r]     = __builtin_amdgcn_exp2f(fmaf(sB0[r], C2, -M2));
                eB[4 + r] = __builtin_amdgcn_exp2f(fmaf(sB1[r], C2, -M2));
            }
            union { shortx8 s8; __hip_bfloat162 h[4]; } pA, pB;
#pragma unroll
            for (int i = 0; i < 4; i++) {
                pA.h[i] = __float22bfloat162_rn(make_float2(eA[2 * i], eA[2 * i + 1]));
                pB.h[i] = __float22bfloat162_rn(make_float2(eB[2 * i], eB[2 * i + 1]));
            }
            oloA = __builtin_amdgcn_mfma_f32_16x16x32_bf16(pA.s8, vlo, oloA, 0, 0, 0);
            ohiA = __builtin_amdgcn_mfma_f32_16x16x32_bf16(pA.s8, vhi, ohiA, 0, 0, 0);
            dsA  = __builtin_amdgcn_mfma_f32_16x16x32_bf16(pA.s8, ones, dsA, 0, 0, 0);
            oloB = __builtin_amdgcn_mfma_f32_16x16x32_bf16(pB.s8, vlo, oloB, 0, 0, 0);
            ohiB = __builtin_amdgcn_mfma_f32_16x16x32_bf16(pB.s8, vhi, ohiB, 0, 0, 0);
            dsB  = __builtin_amdgcn_mfma_f32_16x16x32_bf16(pB.s8, ones, dsB, 0, 0, 0);
        }
        __syncthreads();   // phase p reads done everywhere; stage p+1 landed
    }
    // epilogue: write in A-fragment order (k = channel = h*32 + col)
    const int bi = hi / NH, h = hi % NH;
    const size_t mt0 = (size_t)bi * 64 + (q0 >> 4);      // mtile of tile A
    const int kqlo = l16 >> 3, kr = l16 & 7;
    unsigned short* pAp = aoutf + (mt0 * 12 + h) * 512 + kr;
    unsigned short* pBp = aoutf + ((mt0 + 1) * 12 + h) * 512 + kr;
#pragma unroll
    for (int r = 0; r < 4; r++) {
        const int mrow8 = (quad * 4 + r) * 8;
        const float invA = 1.0f / dsA[r], invB = 1.0f / dsB[r];
        pAp[kqlo * 128 + mrow8]       = f2bf(oloA[r] * invA);
        pAp[(2 + kqlo) * 128 + mrow8] = f2bf(ohiA[r] * invA);
        pBp[kqlo * 128 + mrow8]       = f2bf(oloB[r] * invB);
        pBp[(2 + kqlo) * 128 + mrow8] = f2bf(ohiB[r] * invB);
    }
}

// ---------------------------------------------------------------------------
// Proj GEMM + fp32 bias, fp32 (B, C, N) output. 64x64 block, 4 waves x 32x32,
// grid (128,6) = 768 = 3 blocks/CU exactly, 2-stage prefetch ring.
__global__ __launch_bounds__(256, 3) void k_proj(const unsigned short* __restrict__ aoutf,
                                                 const unsigned short* __restrict__ wpf,
                                                 const float* __restrict__ bias,
                                                 float* __restrict__ out) {
    const int lane = threadIdx.x & 63, w = threadIdx.x >> 6;
    const int quad = lane >> 4, l16 = lane & 15;
    const int m0 = blockIdx.x * 64 + (w & 1) * 32;
    const int n0 = blockIdx.y * 64 + (w >> 1) * 32;
    floatx4 acc[2][2] = {};
    const unsigned short* abase = aoutf + ((size_t)(m0 >> 4) * 48 + quad) * 128 + l16 * 8;
    const unsigned short* bbase = wpf + ((size_t)(n0 >> 4) * 48 + quad) * 128 + l16 * 8;
    shortx8 A0[2], B0[2], A1[2], B1[2];
    ldfrag(A0, B0, abase, bbase, 0);
#pragma unroll
    for (int ks = 0; ks < 12; ks += 2) {
        if (ks + 1 < 12) ldfrag(A1, B1, abase, bbase, ks + 1);
        mmblk(acc, A0, B0);
        if (ks + 2 < 12) ldfrag(A0, B0, abase, bbase, ks + 2);
        mmblk(acc, A1, B1);
    }
    const int bi = m0 >> 10;
#pragma unroll
    for (int sn = 0; sn < 2; sn++) {
        const int o = n0 + sn * 16 + l16;
        const float bv = bias[o];
        float* orow = out + ((size_t)bi * DIM + o) * NT;
#pragma unroll
        for (int sm = 0; sm < 2; sm++) {
            const int nb = (m0 + sm * 16 + quad * 4) & 1023;
            float4 pack;
            pack.x = acc[sm][sn][0] + bv;
            pack.y = acc[sm][sn][1] + bv;
            pack.z = acc[sm][sn][2] + bv;
            pack.w = acc[sm][sn][3] + bv;
            *(float4*)(orow + nb) = pack;
        }
    }
}

// ---------------------------------------------------------------------------
extern "C" void kernel_launch(void* const* d_in, const int* in_sizes, int n_in,
                              void* d_out, int out_size, void* d_ws, size_t ws_size,
                              hipStream_t stream) {
    const float* x     = (const float*)d_in[0];
    const float* wqkv  = (const float*)d_in[1];
    const float* wproj = (const float*)d_in[2];
    const float* bias  = (const float*)d_in[3];
    float* out = (float*)d_out;

    // ws layout (bf16 elems): xtf | qb | kvf | wqf | wpf ; aoutf reuses xtf.
    unsigned short* xtf  = (unsigned short*)d_ws;
    unsigned short* qb   = xtf + 3145728;
    unsigned short* kvf  = qb + 3145728;
    unsigned short* wqf  = kvf + 6291456;    // 96*32*4*512
    unsigned short* wpf  = wqf + 442368;
    unsigned short* aoutf = xtf;             // xtf dead after k_qkv

    k_pre<<<3648, 256, 0, stream>>>(x, wqkv, wproj, xtf, wqf, wpf);
    k_qkv<<<dim3(64, 12), 256, 0, stream>>>(xtf, wqf, qb, kvf);
    k_attn<<<768, 256, 0, stream>>>(qb, kvf, aoutf);
    k_proj<<<dim3(128, 6), 256, 0, stream>>>(aoutf, wpf, bias, out);
}

// Round 11
// 122.025 us; speedup vs baseline: 1.0734x; 1.0014x over previous
//
#include <hip/hip_runtime.h>
#include <hip/hip_bf16.h>

#define DIM   384
#define HD    32
#define NH    12
#define NT    1024            // tokens per batch (32*32)
#define BATCH 8
// p = exp2(s*C2 - M2)  ==  exp(s*SCALE - 8): fixed-max softmax, scale cancels in o/l
#define C2 0.2550347244197545f    // (1/sqrt(32)) * log2(e)
#define M2 11.541560327111707f    // 8 * log2(e)

// Fragment-order layout for a k-major matrix X[row][k], K=384 (12 ksteps):
//   elem addr = ((tile16*12 + kstep)*4 + kgroup)*128 + (row&15)*8 + (k&7)
// KV fragment buffer: kvf[head][tile32][frag][512], frag0/1 = K rows in the
// S^T permutation, frag2/3 = V rows d=0..15 / 16..31 — attention staging
// DMAs are 1KB contiguous.

typedef short shortx8 __attribute__((ext_vector_type(8)));
typedef float floatx4 __attribute__((ext_vector_type(4)));

#define GLD_LDS(gp, lp) \
    __builtin_amdgcn_global_load_lds((__attribute__((address_space(1))) const void*)(gp), \
                                     (__attribute__((address_space(3))) void*)(lp), 16, 0, 0)

static __device__ __forceinline__ unsigned short f2bf(float f) {
    unsigned int u = __float_as_uint(f);
    u += 0x7fffu + ((u >> 16) & 1u);          // round-to-nearest-even
    return (unsigned short)(u >> 16);
}

// fragment-set load / MFMA blocks for the GEMM software-pipeline ring
template <int NA, int NB>
static __device__ __forceinline__ void ldfrag(shortx8 (&A)[NA], shortx8 (&B)[NB],
                                              const unsigned short* ab,
                                              const unsigned short* bb, int ks) {
#pragma unroll
    for (int s = 0; s < NA; s++) A[s] = *(const shortx8*)(ab + s * 6144 + ks * 512);
#pragma unroll
    for (int s = 0; s < NB; s++) B[s] = *(const shortx8*)(bb + s * 6144 + ks * 512);
}
template <int NA, int NB>
static __device__ __forceinline__ void mmblk(floatx4 (&acc)[NA][NB],
                                             const shortx8 (&A)[NA], const shortx8 (&B)[NB]) {
#pragma unroll
    for (int sm = 0; sm < NA; sm++)
#pragma unroll
        for (int sn = 0; sn < NB; sn++)
            acc[sm][sn] = __builtin_amdgcn_mfma_f32_16x16x32_bf16(A[sm], B[sn], acc[sm][sn], 0, 0, 0);
}

// ---------------------------------------------------------------------------
// Fused pre-pass. Blocks [0,3072): x (B,C,N) fp32 -> xtf bf16 A-fragment order
// (float4 tile loads). Blocks [3072,3648): W_qkv/W_proj -> bf16 B-fragment order.
__global__ __launch_bounds__(256) void k_pre(const float* __restrict__ x,
                                             const float* __restrict__ wq,
                                             const float* __restrict__ wp,
                                             unsigned short* __restrict__ xtf,
                                             unsigned short* __restrict__ wqf,
                                             unsigned short* __restrict__ wpf) {
    const int bid = blockIdx.x;
    if (bid < 3072) {
        __shared__ float t[32][33];
        const int xb_ = bid & 31, kstep = (bid >> 5) % 12, b = bid / 384;
        const int n0 = xb_ * 32;
        const int tid = threadIdx.x;
        const int row = tid >> 3, col4 = (tid & 7) * 4;       // one float4/thread
        const float* xb = x + ((size_t)b * DIM + kstep * 32) * NT + n0;
        const float4 v4 = *(const float4*)(xb + (size_t)row * NT + col4);
        t[row][col4 + 0] = v4.x;
        t[row][col4 + 1] = v4.y;
        t[row][col4 + 2] = v4.z;
        t[row][col4 + 3] = v4.w;
        __syncthreads();
        const int mtl = tid >> 7, kq = (tid >> 5) & 3, rem = tid & 31;
        const int mrow = rem >> 1, krH = rem & 1;
        ushort4 p;
        p.x = f2bf(t[kq * 8 + krH * 4 + 0][mtl * 16 + mrow]);
        p.y = f2bf(t[kq * 8 + krH * 4 + 1][mtl * 16 + mrow]);
        p.z = f2bf(t[kq * 8 + krH * 4 + 2][mtl * 16 + mrow]);
        p.w = f2bf(t[kq * 8 + krH * 4 + 3][mtl * 16 + mrow]);
        const size_t mtile = ((size_t)b * 1024 + n0) / 16 + mtl;
        const size_t off = ((mtile * 12 + kstep) * 4 + kq) * 128 + mrow * 8 + krH * 4;
        *(ushort4*)(xtf + off) = p;
    } else {
        const int tid = (bid - 3072) * 256 + threadIdx.x;   // 0..147455
        const float* src; unsigned short* dst; int ci;
        if (tid < 110592) { ci = tid; src = wq; dst = wqf; }
        else              { ci = tid - 110592; src = wp; dst = wpf; }
        const int krH = ci & 1, orow = (ci >> 1) & 15, quad = (ci >> 5) & 3;
        const int t2 = ci >> 7, kstep = t2 % 12, ntile = t2 / 12;
        const int row = ntile * 16 + orow, col = kstep * 32 + quad * 8 + krH * 4;
        const float4 v = *(const float4*)(src + (size_t)row * DIM + col);
        ushort4 p;
        p.x = f2bf(v.x); p.y = f2bf(v.y); p.z = f2bf(v.z); p.w = f2bf(v.w);
        *(ushort4*)(dst + (size_t)ci * 4) = p;
    }
}

// ---------------------------------------------------------------------------
// QKV GEMM. 64x96 block, grid (128,12) = 1536 = 6 blocks/CU (24 waves/CU,
// zero tail), 4 waves x 32x48 (acc[2][3]), 2-stage register prefetch ring.
// Epilogue: q row-major (b,h,n,d); K/V into kvf fragment order (see header).
__global__ __launch_bounds__(256, 6) void k_qkv(const unsigned short* __restrict__ xtf,
                                                const unsigned short* __restrict__ wqf,
                                                unsigned short* __restrict__ qb,
                                                unsigned short* __restrict__ kvf) {
    const int lane = threadIdx.x & 63, w = threadIdx.x >> 6;
    const int quad = lane >> 4, l16 = lane & 15;
    const int m0 = blockIdx.x * 64 + (w & 1) * 32;
    const int n0 = blockIdx.y * 96 + (w >> 1) * 48;
    floatx4 acc[2][3] = {};
    const unsigned short* abase = xtf + ((size_t)(m0 >> 4) * 48 + quad) * 128 + l16 * 8;
    const unsigned short* bbase = wqf + ((size_t)(n0 >> 4) * 48 + quad) * 128 + l16 * 8;
    shortx8 A0[2], B0[3], A1[2], B1[3];
    ldfrag(A0, B0, abase, bbase, 0);
#pragma unroll
    for (int ks = 0; ks < 12; ks += 2) {
        if (ks + 1 < 12) ldfrag(A1, B1, abase, bbase, ks + 1);
        mmblk(acc, A0, B0);
        if (ks + 2 < 12) ldfrag(A0, B0, abase, bbase, ks + 2);
        mmblk(acc, A1, B1);
    }
    const int bi = m0 >> 10;                     // batch constant per block
#pragma unroll
    for (int sn = 0; sn < 3; sn++) {
        const int o = n0 + sn * 16 + l16;        // 0..1151
        const int which = (o >= 2 * DIM) ? 2 : (o >= DIM ? 1 : 0);  // wave-uniform
        const int rem = o - which * DIM;
        const int h = rem >> 5, d = rem & 31;
        const size_t hi = (size_t)bi * NH + h;
#pragma unroll
        for (int sm = 0; sm < 2; sm++) {
            if (which == 2) {
                // V: frag 2/3; 4 consecutive keys (regs) are contiguous elems
                const int nb = m0 + sm * 16 + quad * 4;      // n for r=0
                const int n_ = nb & 1023;
                const int f = 2 + (d >> 4);
                const int ln = (d & 15) + 16 * ((n_ & 31) >> 3);
                ushort4 p;
                p.x = f2bf(acc[sm][sn][0]);
                p.y = f2bf(acc[sm][sn][1]);
                p.z = f2bf(acc[sm][sn][2]);
                p.w = f2bf(acc[sm][sn][3]);
                *(ushort4*)(kvf + ((hi * 32 + (n_ >> 5)) * 4 + f) * 512 + ln * 8 + (n_ & 7)) = p;
            } else {
#pragma unroll
                for (int r = 0; r < 4; r++) {
                    const int n = (m0 + sm * 16 + quad * 4 + r) & 1023;
                    const unsigned short val = f2bf(acc[sm][sn][r]);
                    if (which == 0) {
                        qb[(hi * NT + n) * HD + d] = val;
                    } else {
                        const int key = n & 31;
                        const int kf_ = ((key & 7) < 4) ? 0 : 1;
                        const int kk = key - 4 * kf_;
                        const int l16p = ((kk >> 3) << 2) | (kk & 3);
                        const int pos = (l16p + 16 * (d >> 3)) * 8 + (d & 7);
                        kvf[((hi * 32 + (n >> 5)) * 4 + kf_) * 512 + pos] = val;
                    }
                }
            }
        }
    }
}

// ---------------------------------------------------------------------------
// Flash attention. Block = 1 head x 64 queries, 4 waves x 16 queries; grid
// 1536 = 6 blocks/CU (24 waves/CU). Per phase 2 key-tiles staged into LDS
// (each wave DMAs its fragment type for both tiles), double-buffered 16 KB.
// Fixed-max softmax; denominator via ones-MFMA; A-fragment-order epilogue.
// XCD grouping: all 16 blocks of one head share bid&7.
__global__ __launch_bounds__(256, 6) void k_attn(const unsigned short* __restrict__ qb,
                                                 const unsigned short* __restrict__ kvf,
                                                 unsigned short* __restrict__ aoutf) {
    __shared__ __align__(16) unsigned short frag[2][2][4][512];   // 16 KB
    const int lane = threadIdx.x & 63, w = threadIdx.x >> 6;
    const int quad = lane >> 4, l16 = lane & 15;
    const int g = blockIdx.x & 7, j = blockIdx.x >> 3;   // 1536 blocks
    const int hi = g * 12 + j % 12;                      // head instance b*NH+h
    const int q0 = (j / 12) * 64 + w * 16;               // 16 queries per wave
    const unsigned short* Q = qb + (size_t)hi * NT * HD;

    const shortx8 qf = *(const shortx8*)(Q + (size_t)(q0 + l16) * HD + quad * 8);
    // this wave's staging source: fragment w of each tile, contiguous 1KB
    const unsigned short* gsrc = kvf + ((size_t)hi * 32 * 4 + w) * 512 + lane * 8;
    const int gstep = 4 * 512;                           // elems per 32-key tile

    const shortx8 ones = {16256, 16256, 16256, 16256, 16256, 16256, 16256, 16256}; // bf16 1.0
    floatx4 olo = {}, ohi = {}, ds = {};
    const floatx4 zero = {};

#pragma unroll
    for (int t = 0; t < 2; t++)                          // stage phase 0
        GLD_LDS(gsrc + (size_t)t * gstep, &frag[0][t][w][0]);
    __syncthreads();

    for (int p = 0; p < 16; p++) {
        const int pb = p & 1;
        if (p < 15) {
#pragma unroll
            for (int t = 0; t < 2; t++)                  // stage phase p+1
                GLD_LDS(gsrc + (size_t)((p + 1) * 2 + t) * gstep, &frag[pb ^ 1][t][w][0]);
        }
#pragma unroll
        for (int t = 0; t < 2; t++) {
            const unsigned short* fb = &frag[pb][t][0][0];
            const shortx8 kf0 = *(const shortx8*)(fb + 0 * 512 + lane * 8);
            const shortx8 kf1 = *(const shortx8*)(fb + 1 * 512 + lane * 8);
            const shortx8 vlo = *(const shortx8*)(fb + 2 * 512 + lane * 8);
            const shortx8 vhi = *(const shortx8*)(fb + 3 * 512 + lane * 8);
            const floatx4 s0 = __builtin_amdgcn_mfma_f32_16x16x32_bf16(kf0, qf, zero, 0, 0, 0);
            const floatx4 s1 = __builtin_amdgcn_mfma_f32_16x16x32_bf16(kf1, qf, zero, 0, 0, 0);
            float e[8];
#pragma unroll
            for (int r = 0; r < 4; r++) {
                e[r]     = __builtin_amdgcn_exp2f(fmaf(s0[r], C2, -M2));
                e[4 + r] = __builtin_amdgcn_exp2f(fmaf(s1[r], C2, -M2));
            }
            union { shortx8 s8; __hip_bfloat162 h[4]; } pk;
#pragma unroll
            for (int i = 0; i < 4; i++)
                pk.h[i] = __float22bfloat162_rn(make_float2(e[2 * i], e[2 * i + 1]));
            olo = __builtin_amdgcn_mfma_f32_16x16x32_bf16(pk.s8, vlo, olo, 0, 0, 0);
            ohi = __builtin_amdgcn_mfma_f32_16x16x32_bf16(pk.s8, vhi, ohi, 0, 0, 0);
            ds  = __builtin_amdgcn_mfma_f32_16x16x32_bf16(pk.s8, ones, ds, 0, 0, 0);
        }
        __syncthreads();   // phase p reads done everywhere; stage p+1 landed
    }
    // epilogue: write in A-fragment order (k = channel = h*32 + col)
    const int bi = hi / NH, h = hi % NH;
    const size_t mt0 = (size_t)bi * 64 + (q0 >> 4);      // mtile of this wave
    const int kqlo = l16 >> 3, kr = l16 & 7;
    unsigned short* pp = aoutf + (mt0 * 12 + h) * 512 + kr;
#pragma unroll
    for (int r = 0; r < 4; r++) {
        const int mrow8 = (quad * 4 + r) * 8;
        const float inv = 1.0f / ds[r];
        pp[kqlo * 128 + mrow8]       = f2bf(olo[r] * inv);
        pp[(2 + kqlo) * 128 + mrow8] = f2bf(ohi[r] * inv);
    }
}

// ---------------------------------------------------------------------------
// Proj GEMM + fp32 bias, fp32 (B, C, N) output. 32x128 block, 4 waves x
// 16x32, grid (256,3)... = (256,3)*? -> (256,3) gives 768; use (256,3) with
// 2 n-halves per wave pair: grid (256,3) blocks of 32x128 = 1536? No:
// 8192/32 = 256 m-blocks, 384/128 = 3 n-blocks -> 768 blocks. To reach 1536
// use 32x64 blocks: grid (256,6), 4 waves x 16x32 (2 m-tiles x 2 n-tiles).
__global__ __launch_bounds__(256, 6) void k_proj(const unsigned short* __restrict__ aoutf,
                                                 const unsigned short* __restrict__ wpf,
                                                 const float* __restrict__ bias,
                                                 float* __restrict__ out) {
    const int lane = threadIdx.x & 63, w = threadIdx.x >> 6;
    const int quad = lane >> 4, l16 = lane & 15;
    const int m0 = blockIdx.x * 32 + (w & 1) * 16;
    const int n0 = blockIdx.y * 64 + (w >> 1) * 32;
    floatx4 acc[1][2] = {};
    const unsigned short* abase = aoutf + ((size_t)(m0 >> 4) * 48 + quad) * 128 + l16 * 8;
    const unsigned short* bbase = wpf + ((size_t)(n0 >> 4) * 48 + quad) * 128 + l16 * 8;
    shortx8 A0[1], B0[2], A1[1], B1[2];
    ldfrag(A0, B0, abase, bbase, 0);
#pragma unroll
    for (int ks = 0; ks < 12; ks += 2) {
        if (ks + 1 < 12) ldfrag(A1, B1, abase, bbase, ks + 1);
        mmblk(acc, A0, B0);
        if (ks + 2 < 12) ldfrag(A0, B0, abase, bbase, ks + 2);
        mmblk(acc, A1, B1);
    }
    const int bi = m0 >> 10;
#pragma unroll
    for (int sn = 0; sn < 2; sn++) {
        const int o = n0 + sn * 16 + l16;
        const float bv = bias[o];
        float* orow = out + ((size_t)bi * DIM + o) * NT;
        const int nb = (m0 + quad * 4) & 1023;
        float4 pack;
        pack.x = acc[0][sn][0] + bv;
        pack.y = acc[0][sn][1] + bv;
        pack.z = acc[0][sn][2] + bv;
        pack.w = acc[0][sn][3] + bv;
        *(float4*)(orow + nb) = pack;
    }
}

// ---------------------------------------------------------------------------
extern "C" void kernel_launch(void* const* d_in, const int* in_sizes, int n_in,
                              void* d_out, int out_size, void* d_ws, size_t ws_size,
                              hipStream_t stream) {
    const float* x     = (const float*)d_in[0];
    const float* wqkv  = (const float*)d_in[1];
    const float* wproj = (const float*)d_in[2];
    const float* bias  = (const float*)d_in[3];
    float* out = (float*)d_out;

    // ws layout (bf16 elems): xtf | qb | kvf | wqf | wpf ; aoutf reuses xtf.
    unsigned short* xtf  = (unsigned short*)d_ws;
    unsigned short* qb   = xtf + 3145728;
    unsigned short* kvf  = qb + 3145728;
    unsigned short* wqf  = kvf + 6291456;    // 96*32*4*512
    unsigned short* wpf  = wqf + 442368;
    unsigned short* aoutf = xtf;             // xtf dead after k_qkv

    k_pre<<<3648, 256, 0, stream>>>(x, wqkv, wproj, xtf, wqf, wpf);
    k_qkv<<<dim3(128, 12), 256, 0, stream>>>(xtf, wqf, qb, kvf);
    k_attn<<<1536, 256, 0, stream>>>(qb, kvf, aoutf);
    k_proj<<<dim3(256, 6), 256, 0, stream>>>(aoutf, wpf, bias, out);
}